// Round 9
// baseline (179.135 us; speedup 1.0000x reference)
//
#include <hip/hip_runtime.h>

// 3x3 median blur + residual, zero padding, x:(8,3,1024,1024) f32.
// Round-8 (resubmit; R8 bench was GPUAcquisitionTimeout, never ran):
// R7 copy-clone microstructure + bijective XCD-chunked swizzle.
// R7 result: occupancy 40->74%, service rate 2.5->4.0 TB/s -- but FETCH
// 55->147 MB (1.5x input): round-robin block->XCD mapping puts adjacent
// rows (sharing 2/3 input rows) on different XCDs' non-coherent L2s, so
// every XCD re-fetches. L3 absorbed only half. Fix: flatten grid to 24576
// blocks; XCD k owns contiguous chunk [3072k,3072(k+1)) in plane-major row
// order (3072 rows = exactly 3 planes -> chunk boundary = plane boundary =
// ZERO cross-XCD row sharing). Within an XCD, row reuse distance ~3 blocks
// (~12 KB) << 4 MB L2 -> each input line fetched from HBM once.
// Body unchanged from R7: 3 dwordx4 loads + shfl halos + sort3/med3 + store,
// no LDS, no barrier, 8 blocks/CU (VGPR=16).

typedef float v4f __attribute__((ext_vector_type(4)));

#define S2(a,b) { float _t=fminf(a,b); (b)=fmaxf(a,b); (a)=_t; }
__device__ __forceinline__ float med3f(float a, float b, float c) {
    return fmaxf(fminf(a, b), fminf(fmaxf(a, b), c));
}

constexpr int W = 1024, H = 1024;

__global__ __launch_bounds__(256, 8) void median_blur_kernel(
    const float* __restrict__ xin, float* __restrict__ out)
{
    // ---- bijective XCD-chunked remap (gridDim.x % 8 == 0: 24576/8 = 3072)
    const unsigned orig  = blockIdx.x;
    const unsigned chunk = gridDim.x >> 3;            // blocks per XCD
    const unsigned wg    = (orig & 7u) * chunk + (orig >> 3);
    const int y = (int)(wg & (unsigned)(H - 1));      // row within plane
    const size_t plane = (size_t)(wg >> 10) * (size_t)(H * W);

    const int tx   = threadIdx.x;
    const int lane = tx & 63;
    const int x0   = tx << 2;                         // 4 px per thread
    const float* base = xin + plane;

    const int yt = y > 0     ? y - 1 : 0;             // clamped addr; zeroed below
    const int yb = y < H - 1 ? y + 1 : H - 1;
    const float* rpt = base + ((size_t)yt << 10);
    const float* rpm = base + ((size_t)y  << 10);
    const float* rpb = base + ((size_t)yb << 10);

    // 3 coalesced dwordx4 loads per thread (the whole read side)
    v4f ct = *reinterpret_cast<const v4f*>(rpt + x0);
    v4f cm = *reinterpret_cast<const v4f*>(rpm + x0);
    v4f cb = *reinterpret_cast<const v4f*>(rpb + x0);

    // horizontal halos: intra-wave shfl; wave-boundary lanes load the dword
    float hlt = __shfl_up(ct.w, 1);
    float hlm = __shfl_up(cm.w, 1);
    float hlb = __shfl_up(cb.w, 1);
    float hrt = __shfl_down(ct.x, 1);
    float hrm = __shfl_down(cm.x, 1);
    float hrb = __shfl_down(cb.x, 1);
    if (lane == 0) {
        if (tx == 0) { hlt = 0.0f; hlm = 0.0f; hlb = 0.0f; }   // image left edge
        else         { hlt = rpt[x0 - 1]; hlm = rpm[x0 - 1]; hlb = rpb[x0 - 1]; }
    }
    if (lane == 63) {
        if (tx == 255) { hrt = 0.0f; hrm = 0.0f; hrb = 0.0f; } // image right edge
        else           { hrt = rpt[x0 + 4]; hrm = rpm[x0 + 4]; hrb = rpb[x0 + 4]; }
    }

    float t[6] = { hlt, ct.x, ct.y, ct.z, ct.w, hrt };
    float m[6] = { hlm, cm.x, cm.y, cm.z, cm.w, hrm };
    float b[6] = { hlb, cb.x, cb.y, cb.z, cb.w, hrb };
    if (y == 0) {                                 // input row -1 is zero padding
#pragma unroll
        for (int j = 0; j < 6; ++j) t[j] = 0.0f;
    }
    if (y == H - 1) {                             // input row H is zero padding
#pragma unroll
        for (int j = 0; j < 6; ++j) b[j] = 0.0f;
    }

    // vertical sort3 per column, then med3-of-candidates per output px
    float lo[6], mi[6], hi[6];
#pragma unroll
    for (int j = 0; j < 6; ++j) {
        float a = t[j], c0 = m[j], d = b[j];
        S2(a, c0); S2(c0, d); S2(a, c0);
        lo[j] = a; mi[j] = c0; hi[j] = d;
    }
    v4f o;
#pragma unroll
    for (int j = 0; j < 4; ++j) {
        const float mxlo = fmaxf(lo[j], fmaxf(lo[j + 1], lo[j + 2]));
        const float mnhi = fminf(hi[j], fminf(hi[j + 1], hi[j + 2]));
        const float mdmi = med3f(mi[j], mi[j + 1], mi[j + 2]);
        const float med  = med3f(mxlo, mdmi, mnhi);
        const float xc   = m[j + 1];
        o[j] = xc + 0.2f * (med - xc);
    }
    *reinterpret_cast<v4f*>(out + plane + ((size_t)y << 10) + x0) = o;
}

extern "C" void kernel_launch(void* const* d_in, const int* in_sizes, int n_in,
                              void* d_out, int out_size, void* d_ws, size_t ws_size,
                              hipStream_t stream) {
    const float* x = (const float*)d_in[0];
    float* out = (float*)d_out;
    const int planes = in_sizes[0] / (H * W);     // 24
    dim3 block(256);
    dim3 grid(planes * H);                        // 24576 blocks, 1D, %8==0
    median_blur_kernel<<<grid, block, 0, stream>>>(x, out);
}

// Round 10
// 176.690 us; speedup vs baseline: 1.0138x; 1.0138x over previous
//
#include <hip/hip_runtime.h>

// 3x3 median blur + residual, zero padding, x:(8,3,1024,1024) f32.
// Round-9: shallow multi-row blocks. Cross-round accounting shows duration
// tracks LOGICAL VMEM traffic at ~6.4 TB/s (= m13 copy ceiling per CU),
// not HBM traffic (R9: FETCH 49MB yet still 61us at 400MB logical VMEM).
// Fix: 4 output rows per 256-thread block, 6 input rows loaded ONCE into
// registers (vertical reuse in regs: logical reads 1.5x instead of 3x;
// 240 MB total VMEM vs 400), still fully straight-line one-shot (6
// independent loads -> one natural drain -> 4 rows of compute), no LDS,
// no barrier, no loop-carried state. 4x compute per wave amortizes the
// load->shfl->compute latency chain that kept VALUBusy at 33%.
// Bijective XCD-chunked swizzle kept: grid 6144, chunk 768 blocks = 3072
// rows = exactly 3 planes per XCD -> zero cross-XCD row sharing (R9 proved
// this: FETCH 147->49 MB). __launch_bounds__(256,6): VGPR<=~85 for the
// ~64-reg live set -> 24 waves/CU ceiling.

typedef float v4f __attribute__((ext_vector_type(4)));

#define S2(a,b) { float _t=fminf(a,b); (b)=fmaxf(a,b); (a)=_t; }
__device__ __forceinline__ float med3f(float a, float b, float c) {
    return fmaxf(fminf(a, b), fminf(fmaxf(a, b), c));
}

constexpr int W = 1024, H = 1024;
constexpr int RPB = 4;                    // output rows per block
constexpr int NR  = RPB + 2;              // input rows per block (6)

__global__ __launch_bounds__(256, 6) void median_blur_kernel(
    const float* __restrict__ xin, float* __restrict__ out)
{
    // bijective XCD-chunked remap (gridDim.x = 6144, %8 == 0; chunk = 768
    // blocks = 3 planes per XCD -> chunk boundary == plane boundary)
    const unsigned orig  = blockIdx.x;
    const unsigned chunk = gridDim.x >> 3;
    const unsigned wg    = (orig & 7u) * chunk + (orig >> 3);
    const int    y0    = (int)((wg & 255u) << 2);          // 256 blocks/plane
    const size_t plane = (size_t)(wg >> 8) * (size_t)(H * W);

    const int tx   = threadIdx.x;
    const int lane = tx & 63;
    const int x0   = tx << 2;                              // 4 px per thread
    const float* base = xin + plane;

    // ---- 6 independent coalesced dwordx4 loads (rows y0-1 .. y0+4, clamped)
    v4f c[NR];
#pragma unroll
    for (int s = 0; s < NR; ++s) {
        int y = y0 - 1 + s;
        y = y < 0 ? 0 : (y > H - 1 ? H - 1 : y);           // clamped addr; zeroed below
        c[s] = *reinterpret_cast<const v4f*>(base + ((size_t)y << 10) + x0);
    }

    // ---- horizontal halos: intra-wave shfl; wave-boundary lanes load dwords
    float hl[NR], hr[NR];
#pragma unroll
    for (int s = 0; s < NR; ++s) {
        int y = y0 - 1 + s;
        y = y < 0 ? 0 : (y > H - 1 ? H - 1 : y);
        const float* rp = base + ((size_t)y << 10);
        hl[s] = __shfl_up(c[s].w, 1);
        hr[s] = __shfl_down(c[s].x, 1);
        if (lane == 0)  hl[s] = (tx == 0)   ? 0.0f : rp[x0 - 1];  // image left edge
        if (lane == 63) hr[s] = (tx == 255) ? 0.0f : rp[x0 + 4];  // image right edge
    }

    // ---- vertical zero padding (block-uniform branches)
    if (y0 == 0) {                       // input row -1
        c[0] = (v4f){0.0f, 0.0f, 0.0f, 0.0f}; hl[0] = 0.0f; hr[0] = 0.0f;
    }
    if (y0 == H - RPB) {                 // input row H
        c[NR-1] = (v4f){0.0f, 0.0f, 0.0f, 0.0f}; hl[NR-1] = 0.0f; hr[NR-1] = 0.0f;
    }

    // ---- 4 output rows: column sort3 + med3-of-candidates + residual
#pragma unroll
    for (int r = 0; r < RPB; ++r) {
        const float t[6] = { hl[r],   c[r].x,   c[r].y,   c[r].z,   c[r].w,   hr[r]   };
        const float m[6] = { hl[r+1], c[r+1].x, c[r+1].y, c[r+1].z, c[r+1].w, hr[r+1] };
        const float b[6] = { hl[r+2], c[r+2].x, c[r+2].y, c[r+2].z, c[r+2].w, hr[r+2] };

        float lo[6], mi[6], hi[6];
#pragma unroll
        for (int j = 0; j < 6; ++j) {
            float a = t[j], c0 = m[j], d = b[j];
            S2(a, c0); S2(c0, d); S2(a, c0);
            lo[j] = a; mi[j] = c0; hi[j] = d;
        }
        v4f o;
#pragma unroll
        for (int j = 0; j < 4; ++j) {
            const float mxlo = fmaxf(lo[j], fmaxf(lo[j + 1], lo[j + 2]));
            const float mnhi = fminf(hi[j], fminf(hi[j + 1], hi[j + 2]));
            const float mdmi = med3f(mi[j], mi[j + 1], mi[j + 2]);
            const float med  = med3f(mxlo, mdmi, mnhi);
            const float xc   = m[j + 1];
            o[j] = xc + 0.2f * (med - xc);
        }
        *reinterpret_cast<v4f*>(out + plane + ((size_t)(y0 + r) << 10) + x0) = o;
    }
}

extern "C" void kernel_launch(void* const* d_in, const int* in_sizes, int n_in,
                              void* d_out, int out_size, void* d_ws, size_t ws_size,
                              hipStream_t stream) {
    const float* x = (const float*)d_in[0];
    float* out = (float*)d_out;
    const int planes = in_sizes[0] / (H * W);     // 24
    dim3 block(256);
    dim3 grid(planes * (H / RPB));                // 24 x 256 = 6144 blocks, %8==0
    median_blur_kernel<<<grid, block, 0, stream>>>(x, out);
}

// Round 12
// 174.323 us; speedup vs baseline: 1.0276x; 1.0136x over previous
//
#include <hip/hip_runtime.h>

// 3x3 median blur + residual, zero padding, x:(8,3,1024,1024) f32.
// Round-11 (resubmit; R11 bench was GPUAcquisitionTimeout, never ran).
// Slot-efficiency experiment. Ledger R0-R10: six structurally
// different kernels all run 61-63us while HBM traffic varies 3x, logical
// bytes 1.7x, occupancy 2x. Only the 1-row/block shape (R7/R9) reached the
// m13 per-CU rate (10.5 B/cyc); its vmem mix is 60% junk slots (divergent
// 2-lane halo dwords). Hypothesis: ceiling = vmem INSTRUCTION slots, not
// bytes. This kernel holds traffic at R9's level (3x reads, 400MB logical)
// but makes every vmem instr a perfect 1KB transfer: ONE OUTPUT ROW PER
// WAVE, 16 px/lane in 4 column-chunks of 256 px. 12 coalesced dwordx4
// loads + 4 dwordx4 stores per wave, ZERO divergent halo loads -- all
// horizontal halos are intra-wave (shfl_up/down within chunk, lane-63/0
// broadcast across chunks). No LDS, no barrier, waves independent.
// Bijective XCD chunk swizzle kept (6144 blocks, 768/XCD = exactly 3
// planes -> zero cross-XCD row sharing; R9 proved FETCH 147->49MB).
// __launch_bounds__(256,6): <=85 VGPR for the 48-reg data set + temps.

typedef float v4f __attribute__((ext_vector_type(4)));

#define S2(a,b) { float _t=fminf(a,b); (b)=fmaxf(a,b); (a)=_t; }
__device__ __forceinline__ float med3f(float a, float b, float c) {
    return fmaxf(fminf(a, b), fminf(fmaxf(a, b), c));
}

constexpr int W = 1024, H = 1024;

__global__ __launch_bounds__(256, 6) void median_blur_kernel(
    const float* __restrict__ xin, float* __restrict__ out)
{
    // bijective XCD-chunked remap (gridDim.x = 6144, %8==0; 768 blocks =
    // 3072 rows = exactly 3 planes per XCD -> no cross-XCD row sharing)
    const unsigned orig  = blockIdx.x;
    const unsigned chunk = gridDim.x >> 3;
    const unsigned wg    = (orig & 7u) * chunk + (orig >> 3);

    const int tx   = threadIdx.x;
    const int wv   = tx >> 6;                     // wave 0..3: 4 rows per block
    const int lane = tx & 63;

    const unsigned g = wg * 4u + (unsigned)wv;    // global row id 0..24575
    const int    y     = (int)(g & 1023u);
    const size_t plane = (size_t)(g >> 10) * (size_t)(H * W);
    const float* base  = xin + plane;

    const int yt = y > 0     ? y - 1 : 0;         // clamped; zeroed below
    const int yb = y < H - 1 ? y + 1 : H - 1;
    const float* rpt = base + ((size_t)yt << 10);
    const float* rpm = base + ((size_t)y  << 10);
    const float* rpb = base + ((size_t)yb << 10);

    const int xo = lane << 2;                     // 4 px per lane per chunk

    // ---- 12 perfectly-coalesced dwordx4 loads (3 rows x 4 chunks of 256 px)
    v4f ct[4], cm[4], cb[4];
#pragma unroll
    for (int j = 0; j < 4; ++j) {
        ct[j] = *reinterpret_cast<const v4f*>(rpt + (j << 8) + xo);
        cm[j] = *reinterpret_cast<const v4f*>(rpm + (j << 8) + xo);
        cb[j] = *reinterpret_cast<const v4f*>(rpb + (j << 8) + xo);
    }

    // ---- vertical zero padding (wave-uniform)
    if (y == 0) {
#pragma unroll
        for (int j = 0; j < 4; ++j) ct[j] = (v4f){0.0f, 0.0f, 0.0f, 0.0f};
    }
    if (y == H - 1) {
#pragma unroll
        for (int j = 0; j < 4; ++j) cb[j] = (v4f){0.0f, 0.0f, 0.0f, 0.0f};
    }

    float* o_row = out + plane + ((size_t)y << 10);

    // ---- per chunk: halos purely in-register (shfl + cross-chunk broadcast)
#pragma unroll
    for (int j = 0; j < 4; ++j) {
        // left halo: px j*256 + 4*lane - 1
        float tl_u = __shfl_up(ct[j].w, 1), ml_u = __shfl_up(cm[j].w, 1), bl_u = __shfl_up(cb[j].w, 1);
        float tl_b = (j > 0) ? __shfl(ct[j - 1].w, 63) : 0.0f;   // image left edge -> 0
        float ml_b = (j > 0) ? __shfl(cm[j - 1].w, 63) : 0.0f;
        float bl_b = (j > 0) ? __shfl(cb[j - 1].w, 63) : 0.0f;
        const float tl = (lane == 0) ? tl_b : tl_u;
        const float ml = (lane == 0) ? ml_b : ml_u;
        const float bl = (lane == 0) ? bl_b : bl_u;
        // right halo: px j*256 + 4*lane + 4
        float tr_d = __shfl_down(ct[j].x, 1), mr_d = __shfl_down(cm[j].x, 1), br_d = __shfl_down(cb[j].x, 1);
        float tr_b = (j < 3) ? __shfl(ct[j + 1].x, 0) : 0.0f;    // image right edge -> 0
        float mr_b = (j < 3) ? __shfl(cm[j + 1].x, 0) : 0.0f;
        float br_b = (j < 3) ? __shfl(cb[j + 1].x, 0) : 0.0f;
        const float tr = (lane == 63) ? tr_b : tr_d;
        const float mr = (lane == 63) ? mr_b : mr_d;
        const float br = (lane == 63) ? br_b : br_d;

        const float t[6] = { tl, ct[j].x, ct[j].y, ct[j].z, ct[j].w, tr };
        const float m[6] = { ml, cm[j].x, cm[j].y, cm[j].z, cm[j].w, mr };
        const float b[6] = { bl, cb[j].x, cb[j].y, cb[j].z, cb[j].w, br };

        // vertical sort3 per column, then med3-of-candidates per output px
        float lo[6], mi[6], hi[6];
#pragma unroll
        for (int q = 0; q < 6; ++q) {
            float a = t[q], c0 = m[q], d = b[q];
            S2(a, c0); S2(c0, d); S2(a, c0);
            lo[q] = a; mi[q] = c0; hi[q] = d;
        }
        v4f o;
#pragma unroll
        for (int q = 0; q < 4; ++q) {
            const float mxlo = fmaxf(lo[q], fmaxf(lo[q + 1], lo[q + 2]));
            const float mnhi = fminf(hi[q], fminf(hi[q + 1], hi[q + 2]));
            const float mdmi = med3f(mi[q], mi[q + 1], mi[q + 2]);
            const float med  = med3f(mxlo, mdmi, mnhi);
            const float xc   = m[q + 1];
            o[q] = xc + 0.2f * (med - xc);
        }
        *reinterpret_cast<v4f*>(o_row + (j << 8) + xo) = o;
    }
}

extern "C" void kernel_launch(void* const* d_in, const int* in_sizes, int n_in,
                              void* d_out, int out_size, void* d_ws, size_t ws_size,
                              hipStream_t stream) {
    const float* x = (const float*)d_in[0];
    float* out = (float*)d_out;
    const int planes = in_sizes[0] / (H * W);     // 24
    dim3 block(256);
    dim3 grid(planes * (H / 4));                  // 6144 blocks (4 rows/block), %8==0
    median_blur_kernel<<<grid, block, 0, stream>>>(x, out);
}